// Round 1
// baseline (1304.459 us; speedup 1.0000x reference)
//
#include <hip/hip_runtime.h>

// Relation_5841155522972 — talking-heads attention, straight-through hard select.
// Forward output == hard gather: out[b,i,h*64+d] = v[b, argmax_j n[b,h,i,j], h*64+d]
// where n = LayerNorm_h( softmax_j(QK^T/32) mixed by Wt ).
//
// K1: fp32 QKV projection GEMM (M=4096,N=3072,K=1024); q,k stored transposed
//     per batch (qT/kT[(b*1024+n)*1024 + i]) via LDS transpose epilogue; v straight.
// K2: per (b, 16-row i-tile): two passes over j; pass1 online softmax stats,
//     pass2 recompute scores -> p -> head-mix -> LN -> argmax -> gather v.

#define FMA4(cc, av, bv) \
  cc.x = fmaf(av, bv.x, cc.x); cc.y = fmaf(av, bv.y, cc.y); \
  cc.z = fmaf(av, bv.z, cc.z); cc.w = fmaf(av, bv.w, cc.w);

__global__ __launch_bounds__(256) void qkv_gemm(
    const float* __restrict__ X, const float* __restrict__ Wq,
    const float* __restrict__ Wkv, float* __restrict__ qT,
    float* __restrict__ kT, float* __restrict__ V)
{
  __shared__ __align__(16) float As[16 * 132];
  __shared__ __align__(16) float Bs[16 * 132];
  __shared__ __align__(16) float tb[128 * 32];

  const int t  = threadIdx.x;
  const int bn = blockIdx.x;              // 0..23  (n tiles)
  const int bm = blockIdx.y;              // 0..31  (m tiles)
  const int m0 = bm * 128, n0 = bn * 128;
  const int ty = t >> 4, tx = t & 15;

  const float* Wbase = (n0 < 1024) ? Wq : Wkv;
  const int nw0 = (n0 < 1024) ? n0 : (n0 - 1024);

  float4 c2[8][2];
#pragma unroll
  for (int a = 0; a < 8; a++) {
    c2[a][0] = make_float4(0.f, 0.f, 0.f, 0.f);
    c2[a][1] = make_float4(0.f, 0.f, 0.f, 0.f);
  }

  const int lr = t >> 1;   // 0..127 tile row
  const int lh = t & 1;    // which 8-float half of the 16-wide k-slab

  const float4* As4 = (const float4*)As;
  const float4* Bs4 = (const float4*)Bs;

  for (int kb = 0; kb < 64; kb++) {
    const int k0 = kb * 16;
    __syncthreads();
#pragma unroll
    for (int s = 0; s < 2; s++) {
      const int kk = lh * 8 + s * 4;
      float4 av = *(const float4*)&X[(size_t)(m0 + lr) * 1024 + k0 + kk];
      float4 bv = *(const float4*)&Wbase[(size_t)(nw0 + lr) * 1024 + k0 + kk];
      As[(kk + 0) * 132 + lr] = av.x;
      As[(kk + 1) * 132 + lr] = av.y;
      As[(kk + 2) * 132 + lr] = av.z;
      As[(kk + 3) * 132 + lr] = av.w;
      Bs[(kk + 0) * 132 + lr] = bv.x;
      Bs[(kk + 1) * 132 + lr] = bv.y;
      Bs[(kk + 2) * 132 + lr] = bv.z;
      Bs[(kk + 3) * 132 + lr] = bv.w;
    }
    __syncthreads();
#pragma unroll
    for (int kk = 0; kk < 16; kk++) {
      float4 a0 = As4[kk * 33 + ty * 2];
      float4 a1 = As4[kk * 33 + ty * 2 + 1];
      float4 b0 = Bs4[kk * 33 + tx];
      float4 b1 = Bs4[kk * 33 + 16 + tx];
      FMA4(c2[0][0], a0.x, b0); FMA4(c2[0][1], a0.x, b1);
      FMA4(c2[1][0], a0.y, b0); FMA4(c2[1][1], a0.y, b1);
      FMA4(c2[2][0], a0.z, b0); FMA4(c2[2][1], a0.z, b1);
      FMA4(c2[3][0], a0.w, b0); FMA4(c2[3][1], a0.w, b1);
      FMA4(c2[4][0], a1.x, b0); FMA4(c2[4][1], a1.x, b1);
      FMA4(c2[5][0], a1.y, b0); FMA4(c2[5][1], a1.y, b1);
      FMA4(c2[6][0], a1.z, b0); FMA4(c2[6][1], a1.z, b1);
      FMA4(c2[7][0], a1.w, b0); FMA4(c2[7][1], a1.w, b1);
    }
  }

  if (n0 >= 2048) {
    // v: store straight [m][n]
    const int nv0 = n0 - 2048;
#pragma unroll
    for (int a = 0; a < 8; a++) {
      *(float4*)&V[(size_t)(m0 + ty * 8 + a) * 1024 + nv0 + tx * 4]      = c2[a][0];
      *(float4*)&V[(size_t)(m0 + ty * 8 + a) * 1024 + nv0 + 64 + tx * 4] = c2[a][1];
    }
    return;
  }

  // q / k: transpose 32-col slabs through LDS, store T[(b*1024+n)*1024 + i]
  float* T = (n0 < 1024) ? qT : kT;
  const int nt0 = (n0 < 1024) ? n0 : (n0 - 1024);
  const int bB = m0 >> 10;
  const int i0 = m0 & 1023;
#pragma unroll
  for (int r = 0; r < 4; r++) {
    __syncthreads();
    if ((tx >> 3) == (r & 1)) {
      const int c0 = (tx & 7) * 4;
#pragma unroll
      for (int a = 0; a < 8; a++) {
        const int m = ty * 8 + a;
        float4 val = c2[a][r >> 1];
        tb[m * 32 + ((c0 + 0 + m) & 31)] = val.x;
        tb[m * 32 + ((c0 + 1 + m) & 31)] = val.y;
        tb[m * 32 + ((c0 + 2 + m) & 31)] = val.z;
        tb[m * 32 + ((c0 + 3 + m) & 31)] = val.w;
      }
    }
    __syncthreads();
    const int nl = t >> 3, mq = t & 7;
    float* Trow = T + (size_t)(bB * 1024 + nt0 + (r >> 1) * 64 + (r & 1) * 32 + nl) * 1024 + i0;
#pragma unroll
    for (int l = 0; l < 4; l++) {
      const int mb = (l * 8 + mq) * 4;
      float4 o;
      o.x = tb[(mb + 0) * 32 + ((nl + mb + 0) & 31)];
      o.y = tb[(mb + 1) * 32 + ((nl + mb + 1) & 31)];
      o.z = tb[(mb + 2) * 32 + ((nl + mb + 2) & 31)];
      o.w = tb[(mb + 3) * 32 + ((nl + mb + 3) & 31)];
      *(float4*)(Trow + mb) = o;
    }
  }
}

__global__ __launch_bounds__(256) void attn_fused(
    const float* __restrict__ qT, const float* __restrict__ kT,
    const float* __restrict__ V, const float* __restrict__ Wt,
    const float* __restrict__ ln_g, const float* __restrict__ ln_b,
    float* __restrict__ out)
{
  // qch [h][d16][i16] stride 264 (4224 f) ; kch [h][d16][j32] stride 516 (8256 f)
  // pbuf aliases qch/kch: idx = j*275 + i*17 + h  (8795 f)  — odd strides: bank-clean
  __shared__ __align__(16) float smem[12480];
  float* qch  = smem;
  float* kch  = smem + 4224;
  float* pbuf = smem;

  const int t  = threadIdx.x;
  const int b  = blockIdx.x >> 6;
  const int i0 = (blockIdx.x & 63) << 4;

  // dot-phase ownership: (head h, 4 i-rows, 8 j-cols)
  const int h  = t >> 4;
  const int mi = (t >> 2) & 3;
  const int mj = t & 3;
  const int sd = t & 15;          // staging d within 16-chunk
  // mix-phase ownership: (i-row i2, j-group g, head-quad hq)
  const int i2 = t >> 4;
  const int g  = (t >> 2) & 3;
  const int hq = t & 3;

  const float scale = 0.03125f;   // 1024^-0.5 (exact)

  auto stage = [&](int cc, int jt) {
    const size_t row = (size_t)(b * 1024 + h * 64 + cc * 16 + sd) * 1024;
    const int s = (sd >> 1) & 3;
    const float* qsrc = qT + row + i0;
#pragma unroll
    for (int blk = 0; blk < 4; blk++)
      *(float4*)&qch[h * 264 + sd * 16 + (((blk ^ s) & 3) << 2)] =
          *(const float4*)(qsrc + blk * 4);
    const float* ksrc = kT + row + jt * 32;
#pragma unroll
    for (int blk = 0; blk < 8; blk++)
      *(float4*)&kch[h * 516 + sd * 32 + (((blk ^ s) & 7) << 2)] =
          *(const float4*)(ksrc + blk * 4);
  };

  auto dotstep = [&](float (&acc)[4][8]) {
#pragma unroll
    for (int d = 0; d < 16; d++) {
      const int s = (d >> 1) & 3;
      float4 qv = *(const float4*)&qch[h * 264 + d * 16 + (((mi ^ s) & 3) << 2)];
      float4 ka = *(const float4*)&kch[h * 516 + d * 32 + ((((2 * mj) ^ s) & 7) << 2)];
      float4 kb = *(const float4*)&kch[h * 516 + d * 32 + ((((2 * mj + 1) ^ s) & 7) << 2)];
      const float qa[4] = {qv.x, qv.y, qv.z, qv.w};
#pragma unroll
      for (int ii = 0; ii < 4; ii++) {
        const float qi = qa[ii];
        acc[ii][0] = fmaf(qi, ka.x, acc[ii][0]);
        acc[ii][1] = fmaf(qi, ka.y, acc[ii][1]);
        acc[ii][2] = fmaf(qi, ka.z, acc[ii][2]);
        acc[ii][3] = fmaf(qi, ka.w, acc[ii][3]);
        acc[ii][4] = fmaf(qi, kb.x, acc[ii][4]);
        acc[ii][5] = fmaf(qi, kb.y, acc[ii][5]);
        acc[ii][6] = fmaf(qi, kb.z, acc[ii][6]);
        acc[ii][7] = fmaf(qi, kb.w, acc[ii][7]);
      }
    }
  };

  float m_run[4], l_run[4];
#pragma unroll
  for (int ii = 0; ii < 4; ii++) { m_run[ii] = -1e30f; l_run[ii] = 0.f; }

  // ---------------- pass 1: online softmax stats ----------------
  for (int jt = 0; jt < 32; jt++) {
    float acc[4][8];
#pragma unroll
    for (int ii = 0; ii < 4; ii++) {
#pragma unroll
      for (int jj = 0; jj < 8; jj++) acc[ii][jj] = 0.f;
    }
    for (int cc = 0; cc < 4; cc++) {
      __syncthreads();
      stage(cc, jt);
      __syncthreads();
      dotstep(acc);
    }
#pragma unroll
    for (int ii = 0; ii < 4; ii++) {
      float tm = acc[ii][0];
#pragma unroll
      for (int jj = 1; jj < 8; jj++) tm = fmaxf(tm, acc[ii][jj]);
      tm *= scale;
      tm = fmaxf(tm, __shfl_xor(tm, 1));
      tm = fmaxf(tm, __shfl_xor(tm, 2));
      const float mn = fmaxf(m_run[ii], tm);
      float ss = 0.f;
#pragma unroll
      for (int jj = 0; jj < 8; jj++) ss += __expf(acc[ii][jj] * scale - mn);
      ss += __shfl_xor(ss, 1);
      ss += __shfl_xor(ss, 2);
      l_run[ii] = l_run[ii] * __expf(m_run[ii] - mn) + ss;
      m_run[ii] = mn;
    }
  }
  float rl[4];
#pragma unroll
  for (int ii = 0; ii < 4; ii++) rl[ii] = 1.0f / l_run[ii];

  // mix-phase constants: 4 Wt rows + LN affine per thread (registers)
  float wtr[4][16], gr[4], br[4];
#pragma unroll
  for (int a = 0; a < 4; a++) {
#pragma unroll
    for (int h2 = 0; h2 < 16; h2++) wtr[a][h2] = Wt[(hq * 4 + a) * 16 + h2];
    gr[a] = ln_g[hq * 4 + a];
    br[a] = ln_b[hq * 4 + a];
  }
  float bv[4]; int bix[4];
#pragma unroll
  for (int a = 0; a < 4; a++) { bv[a] = -1e30f; bix[a] = 0; }

  // ---------------- pass 2: p -> mix -> LN -> argmax ----------------
  for (int jt = 0; jt < 32; jt++) {
    float acc[4][8];
#pragma unroll
    for (int ii = 0; ii < 4; ii++) {
#pragma unroll
      for (int jj = 0; jj < 8; jj++) acc[ii][jj] = 0.f;
    }
    for (int cc = 0; cc < 4; cc++) {
      __syncthreads();
      stage(cc, jt);
      __syncthreads();
      dotstep(acc);
    }
    __syncthreads();   // qch/kch reads done before pbuf (alias) writes
#pragma unroll
    for (int ii = 0; ii < 4; ii++) {
#pragma unroll
      for (int jj = 0; jj < 8; jj++) {
        const float p = __expf(acc[ii][jj] * scale - m_run[ii]) * rl[ii];
        pbuf[(mj * 8 + jj) * 275 + (mi * 4 + ii) * 17 + h] = p;
      }
    }
    __syncthreads();
#pragma unroll
    for (int jj = 0; jj < 8; jj++) {
      const int j = g * 8 + jj;
      float pv[16];
#pragma unroll
      for (int h2 = 0; h2 < 16; h2++) pv[h2] = pbuf[j * 275 + i2 * 17 + h2];
      float mix[4];
#pragma unroll
      for (int a = 0; a < 4; a++) {
        float s0 = 0.f;
#pragma unroll
        for (int h2 = 0; h2 < 16; h2++) s0 = fmaf(pv[h2], wtr[a][h2], s0);
        mix[a] = s0;
      }
      float s1 = mix[0] + mix[1] + mix[2] + mix[3];
      s1 += __shfl_xor(s1, 1);
      s1 += __shfl_xor(s1, 2);
      const float mu = s1 * 0.0625f;
      float s2 = 0.f;
#pragma unroll
      for (int a = 0; a < 4; a++) { const float dd = mix[a] - mu; s2 = fmaf(dd, dd, s2); }
      s2 += __shfl_xor(s2, 1);
      s2 += __shfl_xor(s2, 2);
      const float rstd = rsqrtf(s2 * 0.0625f + 1e-5f);
      const int jg = jt * 32 + j;
#pragma unroll
      for (int a = 0; a < 4; a++) {
        const float nv = (mix[a] - mu) * rstd * gr[a] + br[a];
        if (nv > bv[a]) { bv[a] = nv; bix[a] = jg; }
      }
    }
  }

  // merge argmax over the 4 g-lanes; ties -> smaller j (first occurrence)
#pragma unroll
  for (int a = 0; a < 4; a++) {
    float v = bv[a]; int ix = bix[a];
    {
      const float ov = __shfl_xor(v, 4);
      const int oi = __shfl_xor(ix, 4);
      if (ov > v || (ov == v && oi < ix)) { v = ov; ix = oi; }
    }
    {
      const float ov = __shfl_xor(v, 8);
      const int oi = __shfl_xor(ix, 8);
      if (ov > v || (ov == v && oi < ix)) { v = ov; ix = oi; }
    }
    bv[a] = v; bix[a] = ix;
  }

  // gather: thread covers (row i2, heads hq*4+a, d in [g*16, g*16+16))
#pragma unroll
  for (int a = 0; a < 4; a++) {
    const int hp = hq * 4 + a;
    const float* vs = V + (size_t)(b * 1024 + bix[a]) * 1024 + hp * 64 + g * 16;
    float* dst = out + (size_t)(b * 1024 + i0 + i2) * 1024 + hp * 64 + g * 16;
#pragma unroll
    for (int w = 0; w < 4; w++)
      *(float4*)(dst + w * 4) = *(const float4*)(vs + w * 4);
  }
}

extern "C" void kernel_launch(void* const* d_in, const int* in_sizes, int n_in,
                              void* d_out, int out_size, void* d_ws, size_t ws_size,
                              hipStream_t stream) {
  const float* x   = (const float*)d_in[0];
  const float* Wq  = (const float*)d_in[1];
  const float* Wkv = (const float*)d_in[2];
  const float* Wt  = (const float*)d_in[3];
  const float* lng = (const float*)d_in[4];
  const float* lnb = (const float*)d_in[5];
  float* out = (float*)d_out;
  float* ws  = (float*)d_ws;                 // needs 48 MB
  float* qT = ws;                            // [b][n][i] 4M floats
  float* kT = ws + (size_t)4 * 1024 * 1024;  // [b][n][i] 4M floats
  float* V  = ws + (size_t)8 * 1024 * 1024;  // [m][n]    4M floats

  hipLaunchKernelGGL(qkv_gemm, dim3(24, 32), dim3(256), 0, stream,
                     x, Wq, Wkv, qT, kT, V);
  hipLaunchKernelGGL(attn_fused, dim3(256), dim3(256), 0, stream,
                     qT, kT, V, Wt, lng, lnb, out);
}

// Round 2
// 1270.276 us; speedup vs baseline: 1.0269x; 1.0269x over previous
//
#include <hip/hip_runtime.h>

// Relation_5841155522972 — talking-heads attention, straight-through hard select.
// Forward output == hard gather: out[b,i,h*64+d] = v[b, argmax_j n[b,h,i,j], h*64+d]
// where n = LayerNorm_h( softmax_j(QK^T/32) mixed by Wt ).
//
// R2 structure:
//  K1  qkv_gemm     : fp32 QKV projection (M=4096,N=3072,K=1024); qT/kT transposed, V straight.
//  K2a attn_stats   : grid (b × 64 i-tiles × 4 j-slices) partial softmax stats (m,l).
//  K2b attn_select  : same grid; merge stats, recompute slice dots, p->mix->LN->local argmax.
//  K2c merge_gather : 4-way argmax merge + V gather.
// R1 failure mode fixed here: attn kernel had grid=256 (1 wg/CU, Occ 11.5%, VALU 19%).

#define FMA4(cc, av, bv) \
  cc.x = fmaf(av, bv.x, cc.x); cc.y = fmaf(av, bv.y, cc.y); \
  cc.z = fmaf(av, bv.z, cc.z); cc.w = fmaf(av, bv.w, cc.w);

__global__ __launch_bounds__(256) void qkv_gemm(
    const float* __restrict__ X, const float* __restrict__ Wq,
    const float* __restrict__ Wkv, float* __restrict__ qT,
    float* __restrict__ kT, float* __restrict__ V)
{
  __shared__ __align__(16) float As[16 * 132];
  __shared__ __align__(16) float Bs[16 * 132];
  __shared__ __align__(16) float tb[128 * 32];

  const int t  = threadIdx.x;
  const int bn = blockIdx.x;              // 0..23  (n tiles)
  const int bm = blockIdx.y;              // 0..31  (m tiles)
  const int m0 = bm * 128, n0 = bn * 128;
  const int ty = t >> 4, tx = t & 15;

  const float* Wbase = (n0 < 1024) ? Wq : Wkv;
  const int nw0 = (n0 < 1024) ? n0 : (n0 - 1024);

  float4 c2[8][2];
#pragma unroll
  for (int a = 0; a < 8; a++) {
    c2[a][0] = make_float4(0.f, 0.f, 0.f, 0.f);
    c2[a][1] = make_float4(0.f, 0.f, 0.f, 0.f);
  }

  const int lr = t >> 1;   // 0..127 tile row
  const int lh = t & 1;    // which 8-float half of the 16-wide k-slab

  const float4* As4 = (const float4*)As;
  const float4* Bs4 = (const float4*)Bs;

  for (int kb = 0; kb < 64; kb++) {
    const int k0 = kb * 16;
    __syncthreads();
#pragma unroll
    for (int s = 0; s < 2; s++) {
      const int kk = lh * 8 + s * 4;
      float4 av = *(const float4*)&X[(size_t)(m0 + lr) * 1024 + k0 + kk];
      float4 bv = *(const float4*)&Wbase[(size_t)(nw0 + lr) * 1024 + k0 + kk];
      As[(kk + 0) * 132 + lr] = av.x;
      As[(kk + 1) * 132 + lr] = av.y;
      As[(kk + 2) * 132 + lr] = av.z;
      As[(kk + 3) * 132 + lr] = av.w;
      Bs[(kk + 0) * 132 + lr] = bv.x;
      Bs[(kk + 1) * 132 + lr] = bv.y;
      Bs[(kk + 2) * 132 + lr] = bv.z;
      Bs[(kk + 3) * 132 + lr] = bv.w;
    }
    __syncthreads();
#pragma unroll
    for (int kk = 0; kk < 16; kk++) {
      float4 a0 = As4[kk * 33 + ty * 2];
      float4 a1 = As4[kk * 33 + ty * 2 + 1];
      float4 b0 = Bs4[kk * 33 + tx];
      float4 b1 = Bs4[kk * 33 + 16 + tx];
      FMA4(c2[0][0], a0.x, b0); FMA4(c2[0][1], a0.x, b1);
      FMA4(c2[1][0], a0.y, b0); FMA4(c2[1][1], a0.y, b1);
      FMA4(c2[2][0], a0.z, b0); FMA4(c2[2][1], a0.z, b1);
      FMA4(c2[3][0], a0.w, b0); FMA4(c2[3][1], a0.w, b1);
      FMA4(c2[4][0], a1.x, b0); FMA4(c2[4][1], a1.x, b1);
      FMA4(c2[5][0], a1.y, b0); FMA4(c2[5][1], a1.y, b1);
      FMA4(c2[6][0], a1.z, b0); FMA4(c2[6][1], a1.z, b1);
      FMA4(c2[7][0], a1.w, b0); FMA4(c2[7][1], a1.w, b1);
    }
  }

  if (n0 >= 2048) {
    const int nv0 = n0 - 2048;
#pragma unroll
    for (int a = 0; a < 8; a++) {
      *(float4*)&V[(size_t)(m0 + ty * 8 + a) * 1024 + nv0 + tx * 4]      = c2[a][0];
      *(float4*)&V[(size_t)(m0 + ty * 8 + a) * 1024 + nv0 + 64 + tx * 4] = c2[a][1];
    }
    return;
  }

  // q / k: transpose 32-col slabs through LDS, store T[(b*1024+n)*1024 + i]
  float* T = (n0 < 1024) ? qT : kT;
  const int nt0 = (n0 < 1024) ? n0 : (n0 - 1024);
  const int bB = m0 >> 10;
  const int i0 = m0 & 1023;
#pragma unroll
  for (int r = 0; r < 4; r++) {
    __syncthreads();
    if ((tx >> 3) == (r & 1)) {
      const int c0 = (tx & 7) * 4;
#pragma unroll
      for (int a = 0; a < 8; a++) {
        const int m = ty * 8 + a;
        float4 val = c2[a][r >> 1];
        tb[m * 32 + ((c0 + 0 + m) & 31)] = val.x;
        tb[m * 32 + ((c0 + 1 + m) & 31)] = val.y;
        tb[m * 32 + ((c0 + 2 + m) & 31)] = val.z;
        tb[m * 32 + ((c0 + 3 + m) & 31)] = val.w;
      }
    }
    __syncthreads();
    const int nl = t >> 3, mq = t & 7;
    float* Trow = T + (size_t)(bB * 1024 + nt0 + (r >> 1) * 64 + (r & 1) * 32 + nl) * 1024 + i0;
#pragma unroll
    for (int l = 0; l < 4; l++) {
      const int mb = (l * 8 + mq) * 4;
      float4 o;
      o.x = tb[(mb + 0) * 32 + ((nl + mb + 0) & 31)];
      o.y = tb[(mb + 1) * 32 + ((nl + mb + 1) & 31)];
      o.z = tb[(mb + 2) * 32 + ((nl + mb + 2) & 31)];
      o.w = tb[(mb + 3) * 32 + ((nl + mb + 3) & 31)];
      *(float4*)(Trow + mb) = o;
    }
  }
}

// ---------------------------------------------------------------------------
// K2a: partial softmax stats per (b, 16-i tile, 256-j slice).
// ---------------------------------------------------------------------------
__global__ __launch_bounds__(256) void attn_stats(
    const float* __restrict__ qT, const float* __restrict__ kT,
    float* __restrict__ Mm, float* __restrict__ Ml)
{
  __shared__ __align__(16) float smem[12480];
  float* qch = smem;          // [h][d16][i16] stride 264
  float* kch = smem + 4224;   // [h][d16][j32] stride 516

  const int t  = threadIdx.x;
  const int bx = blockIdx.x;
  const int b  = bx >> 8;
  const int it = (bx >> 2) & 63;
  const int js = bx & 3;
  const int i0 = it << 4;

  const int h  = t >> 4;
  const int mi = (t >> 2) & 3;
  const int mj = t & 3;
  const int sd = t & 15;

  const float scale = 0.03125f;

  auto stage = [&](int cc, int jt) {
    const size_t row = (size_t)(b * 1024 + h * 64 + cc * 16 + sd) * 1024;
    const int s = (sd >> 1) & 3;
    const float* qsrc = qT + row + i0;
#pragma unroll
    for (int blk = 0; blk < 4; blk++)
      *(float4*)&qch[h * 264 + sd * 16 + (((blk ^ s) & 3) << 2)] =
          *(const float4*)(qsrc + blk * 4);
    const float* ksrc = kT + row + jt * 32;
#pragma unroll
    for (int blk = 0; blk < 8; blk++)
      *(float4*)&kch[h * 516 + sd * 32 + (((blk ^ s) & 7) << 2)] =
          *(const float4*)(ksrc + blk * 4);
  };

  auto dotstep = [&](float (&acc)[4][8]) {
#pragma unroll
    for (int d = 0; d < 16; d++) {
      const int s = (d >> 1) & 3;
      float4 qv = *(const float4*)&qch[h * 264 + d * 16 + (((mi ^ s) & 3) << 2)];
      float4 ka = *(const float4*)&kch[h * 516 + d * 32 + ((((2 * mj) ^ s) & 7) << 2)];
      float4 kb = *(const float4*)&kch[h * 516 + d * 32 + ((((2 * mj + 1) ^ s) & 7) << 2)];
      const float qa[4] = {qv.x, qv.y, qv.z, qv.w};
#pragma unroll
      for (int ii = 0; ii < 4; ii++) {
        const float qi = qa[ii];
        acc[ii][0] = fmaf(qi, ka.x, acc[ii][0]);
        acc[ii][1] = fmaf(qi, ka.y, acc[ii][1]);
        acc[ii][2] = fmaf(qi, ka.z, acc[ii][2]);
        acc[ii][3] = fmaf(qi, ka.w, acc[ii][3]);
        acc[ii][4] = fmaf(qi, kb.x, acc[ii][4]);
        acc[ii][5] = fmaf(qi, kb.y, acc[ii][5]);
        acc[ii][6] = fmaf(qi, kb.z, acc[ii][6]);
        acc[ii][7] = fmaf(qi, kb.w, acc[ii][7]);
      }
    }
  };

  float m_run[4], l_run[4];
#pragma unroll
  for (int ii = 0; ii < 4; ii++) { m_run[ii] = -1e30f; l_run[ii] = 0.f; }

  for (int jtl = 0; jtl < 8; jtl++) {
    const int jt = js * 8 + jtl;
    float acc[4][8];
#pragma unroll
    for (int ii = 0; ii < 4; ii++)
#pragma unroll
      for (int jj = 0; jj < 8; jj++) acc[ii][jj] = 0.f;
    for (int cc = 0; cc < 4; cc++) {
      __syncthreads();
      stage(cc, jt);
      __syncthreads();
      dotstep(acc);
    }
#pragma unroll
    for (int ii = 0; ii < 4; ii++) {
      float tm = acc[ii][0];
#pragma unroll
      for (int jj = 1; jj < 8; jj++) tm = fmaxf(tm, acc[ii][jj]);
      tm *= scale;
      tm = fmaxf(tm, __shfl_xor(tm, 1));
      tm = fmaxf(tm, __shfl_xor(tm, 2));
      const float mn = fmaxf(m_run[ii], tm);
      float ss = 0.f;
#pragma unroll
      for (int jj = 0; jj < 8; jj++) ss += __expf(acc[ii][jj] * scale - mn);
      ss += __shfl_xor(ss, 1);
      ss += __shfl_xor(ss, 2);
      l_run[ii] = l_run[ii] * __expf(m_run[ii] - mn) + ss;
      m_run[ii] = mn;
    }
  }

  if (mj == 0) {
#pragma unroll
    for (int ii = 0; ii < 4; ii++) {
      const int idx = bx * 256 + h * 16 + mi * 4 + ii;
      Mm[idx] = m_run[ii];
      Ml[idx] = l_run[ii];
    }
  }
}

// ---------------------------------------------------------------------------
// K2b: merge stats, recompute slice dots, p -> mix -> LN -> local argmax.
// ---------------------------------------------------------------------------
__global__ __launch_bounds__(256) void attn_select(
    const float* __restrict__ qT, const float* __restrict__ kT,
    const float* __restrict__ Wt, const float* __restrict__ ln_g,
    const float* __restrict__ ln_b, const float* __restrict__ Mm,
    const float* __restrict__ Ml, float* __restrict__ Aval,
    int* __restrict__ Aidx)
{
  __shared__ __align__(16) float smem[12992];
  float* qch  = smem;           // aliased by pbuf
  float* kch  = smem + 4224;
  float* pbuf = smem;           // j*275 + i*17 + h
  float* mred = smem + 12480;   // [h*16+i] final m
  float* rred = smem + 12736;   // [h*16+i] 1/l

  const int t  = threadIdx.x;
  const int bx = blockIdx.x;
  const int b  = bx >> 8;
  const int it = (bx >> 2) & 63;
  const int js = bx & 3;
  const int i0 = it << 4;

  const int h  = t >> 4;
  const int mi = (t >> 2) & 3;
  const int mj = t & 3;
  const int sd = t & 15;
  const int i2 = t >> 4;
  const int g  = (t >> 2) & 3;
  const int hq = t & 3;

  const float scale = 0.03125f;

  // ---- merge the 4 slice partial stats (t == h*16 + i exactly) ----
  {
    const int base = ((b * 64 + it) << 2) * 256 + t;
    float m4[4], l4[4];
#pragma unroll
    for (int s = 0; s < 4; s++) { m4[s] = Mm[base + s * 256]; l4[s] = Ml[base + s * 256]; }
    float M = fmaxf(fmaxf(m4[0], m4[1]), fmaxf(m4[2], m4[3]));
    float L = 0.f;
#pragma unroll
    for (int s = 0; s < 4; s++) L += l4[s] * __expf(m4[s] - M);
    mred[t] = M;
    rred[t] = 1.0f / L;
  }
  __syncthreads();
  float m_fin[4], rl_fin[4];
#pragma unroll
  for (int ii = 0; ii < 4; ii++) {
    m_fin[ii]  = mred[h * 16 + mi * 4 + ii];
    rl_fin[ii] = rred[h * 16 + mi * 4 + ii];
  }

  auto stage = [&](int cc, int jt) {
    const size_t row = (size_t)(b * 1024 + h * 64 + cc * 16 + sd) * 1024;
    const int s = (sd >> 1) & 3;
    const float* qsrc = qT + row + i0;
#pragma unroll
    for (int blk = 0; blk < 4; blk++)
      *(float4*)&qch[h * 264 + sd * 16 + (((blk ^ s) & 3) << 2)] =
          *(const float4*)(qsrc + blk * 4);
    const float* ksrc = kT + row + jt * 32;
#pragma unroll
    for (int blk = 0; blk < 8; blk++)
      *(float4*)&kch[h * 516 + sd * 32 + (((blk ^ s) & 7) << 2)] =
          *(const float4*)(ksrc + blk * 4);
  };

  auto dotstep = [&](float (&acc)[4][8]) {
#pragma unroll
    for (int d = 0; d < 16; d++) {
      const int s = (d >> 1) & 3;
      float4 qv = *(const float4*)&qch[h * 264 + d * 16 + (((mi ^ s) & 3) << 2)];
      float4 ka = *(const float4*)&kch[h * 516 + d * 32 + ((((2 * mj) ^ s) & 7) << 2)];
      float4 kb = *(const float4*)&kch[h * 516 + d * 32 + ((((2 * mj + 1) ^ s) & 7) << 2)];
      const float qa[4] = {qv.x, qv.y, qv.z, qv.w};
#pragma unroll
      for (int ii = 0; ii < 4; ii++) {
        const float qi = qa[ii];
        acc[ii][0] = fmaf(qi, ka.x, acc[ii][0]);
        acc[ii][1] = fmaf(qi, ka.y, acc[ii][1]);
        acc[ii][2] = fmaf(qi, ka.z, acc[ii][2]);
        acc[ii][3] = fmaf(qi, ka.w, acc[ii][3]);
        acc[ii][4] = fmaf(qi, kb.x, acc[ii][4]);
        acc[ii][5] = fmaf(qi, kb.y, acc[ii][5]);
        acc[ii][6] = fmaf(qi, kb.z, acc[ii][6]);
        acc[ii][7] = fmaf(qi, kb.w, acc[ii][7]);
      }
    }
  };

  float wtr[4][16], gr[4], br[4];
#pragma unroll
  for (int a = 0; a < 4; a++) {
#pragma unroll
    for (int h2 = 0; h2 < 16; h2++) wtr[a][h2] = Wt[(hq * 4 + a) * 16 + h2];
    gr[a] = ln_g[hq * 4 + a];
    br[a] = ln_b[hq * 4 + a];
  }
  float bv[4]; int bix[4];
#pragma unroll
  for (int a = 0; a < 4; a++) { bv[a] = -1e30f; bix[a] = 0; }

  for (int jtl = 0; jtl < 8; jtl++) {
    const int jt = js * 8 + jtl;
    float acc[4][8];
#pragma unroll
    for (int ii = 0; ii < 4; ii++)
#pragma unroll
      for (int jj = 0; jj < 8; jj++) acc[ii][jj] = 0.f;
    for (int cc = 0; cc < 4; cc++) {
      __syncthreads();
      stage(cc, jt);
      __syncthreads();
      dotstep(acc);
    }
    __syncthreads();   // qch/kch reads done before pbuf (alias) writes
#pragma unroll
    for (int ii = 0; ii < 4; ii++) {
#pragma unroll
      for (int jj = 0; jj < 8; jj++) {
        const float p = __expf(acc[ii][jj] * scale - m_fin[ii]) * rl_fin[ii];
        pbuf[(mj * 8 + jj) * 275 + (mi * 4 + ii) * 17 + h] = p;
      }
    }
    __syncthreads();
#pragma unroll
    for (int jj = 0; jj < 8; jj++) {
      const int j = g * 8 + jj;
      float pv[16];
#pragma unroll
      for (int h2 = 0; h2 < 16; h2++) pv[h2] = pbuf[j * 275 + i2 * 17 + h2];
      float mix[4];
#pragma unroll
      for (int a = 0; a < 4; a++) {
        float s0 = 0.f;
#pragma unroll
        for (int h2 = 0; h2 < 16; h2++) s0 = fmaf(pv[h2], wtr[a][h2], s0);
        mix[a] = s0;
      }
      float s1 = mix[0] + mix[1] + mix[2] + mix[3];
      s1 += __shfl_xor(s1, 1);
      s1 += __shfl_xor(s1, 2);
      const float mu = s1 * 0.0625f;
      float s2 = 0.f;
#pragma unroll
      for (int a = 0; a < 4; a++) { const float dd = mix[a] - mu; s2 = fmaf(dd, dd, s2); }
      s2 += __shfl_xor(s2, 1);
      s2 += __shfl_xor(s2, 2);
      const float rstd = rsqrtf(s2 * 0.0625f + 1e-5f);
      const int jg = jt * 32 + j;
#pragma unroll
      for (int a = 0; a < 4; a++) {
        const float nv = (mix[a] - mu) * rstd * gr[a] + br[a];
        if (nv > bv[a]) { bv[a] = nv; bix[a] = jg; }
      }
    }
  }

  // merge argmax over the 4 g-lanes; ties -> smaller j (first occurrence)
#pragma unroll
  for (int a = 0; a < 4; a++) {
    float v = bv[a]; int ix = bix[a];
    {
      const float ov = __shfl_xor(v, 4);
      const int oi = __shfl_xor(ix, 4);
      if (ov > v || (ov == v && oi < ix)) { v = ov; ix = oi; }
    }
    {
      const float ov = __shfl_xor(v, 8);
      const int oi = __shfl_xor(ix, 8);
      if (ov > v || (ov == v && oi < ix)) { v = ov; ix = oi; }
    }
    bv[a] = v; bix[a] = ix;
  }

  if (g == 0) {
#pragma unroll
    for (int a = 0; a < 4; a++) {
      const int idx = bx * 256 + (hq * 4 + a) * 16 + i2;
      Aval[idx] = bv[a];
      Aidx[idx] = bix[a];
    }
  }
}

// ---------------------------------------------------------------------------
// K2c: merge the 4 j-slices' argmax, gather V rows to out.
// ---------------------------------------------------------------------------
__global__ __launch_bounds__(256) void merge_gather(
    const float* __restrict__ Aval, const int* __restrict__ Aidx,
    const float* __restrict__ V, float* __restrict__ out)
{
  const int t  = threadIdx.x;
  const int bx = blockIdx.x;           // 0..255
  const int b  = bx >> 6;
  const int it = bx & 63;
  const int i2 = t >> 4;
  const int h  = t & 15;

  const int base = ((b * 64 + it) << 2) * 256 + h * 16 + i2;
  float bvv = Aval[base];
  int   bii = Aidx[base];
#pragma unroll
  for (int s = 1; s < 4; s++) {
    const float v = Aval[base + s * 256];
    const int   x = Aidx[base + s * 256];
    if (v > bvv) { bvv = v; bii = x; }   // slices are j-ordered: strict > keeps first max
  }

  const float* vs = V + (size_t)(b * 1024 + bii) * 1024 + h * 64;
  float* dst = out + (size_t)(b * 1024 + it * 16 + i2) * 1024 + h * 64;
#pragma unroll
  for (int w = 0; w < 16; w++)
    *(float4*)(dst + w * 4) = *(const float4*)(vs + w * 4);
}

extern "C" void kernel_launch(void* const* d_in, const int* in_sizes, int n_in,
                              void* d_out, int out_size, void* d_ws, size_t ws_size,
                              hipStream_t stream) {
  const float* x   = (const float*)d_in[0];
  const float* Wq  = (const float*)d_in[1];
  const float* Wkv = (const float*)d_in[2];
  const float* Wt  = (const float*)d_in[3];
  const float* lng = (const float*)d_in[4];
  const float* lnb = (const float*)d_in[5];
  float* out = (float*)d_out;
  float* ws  = (float*)d_ws;                     // needs ~52 MB
  float* qT   = ws;                              // [b][n][i]  4M floats
  float* kT   = ws + (size_t)4 * 1024 * 1024;    // [b][n][i]  4M floats
  float* V    = ws + (size_t)8 * 1024 * 1024;    // [m][n]     4M floats
  float* Mm   = ws + (size_t)12 * 1024 * 1024;   // 256K
  float* Ml   = Mm + 262144;                     // 256K
  float* Aval = Mm + 524288;                     // 256K
  int*   Aidx = (int*)(Mm + 786432);             // 256K

  hipLaunchKernelGGL(qkv_gemm, dim3(24, 32), dim3(256), 0, stream,
                     x, Wq, Wkv, qT, kT, V);
  hipLaunchKernelGGL(attn_stats, dim3(1024), dim3(256), 0, stream,
                     qT, kT, Mm, Ml);
  hipLaunchKernelGGL(attn_select, dim3(1024), dim3(256), 0, stream,
                     qT, kT, Wt, lng, lnb, Mm, Ml, Aval, Aidx);
  hipLaunchKernelGGL(merge_gather, dim3(256), dim3(256), 0, stream,
                     Aval, Aidx, V, out);
}

// Round 3
// 1143.308 us; speedup vs baseline: 1.1410x; 1.1111x over previous
//
#include <hip/hip_runtime.h>

// Relation_5841155522972 — talking-heads attention, straight-through hard select.
// out[b,i,h*64+d] = v[b, argmax_j n[b,h,i,j], h*64+d],
// n = LayerNorm_h( softmax_j(QK^T/32) mixed by Wt ).
//
// R3:
//  K1  qkv_gemm      : unchanged (fp32 GEMM, qT/kT transposed, V straight).
//  K2a attn_stats_v3 : h-loop dot; wave=8i x 128j; k dbuf in LDS (1 ds_read_b64
//                      per 16 FMA), q via wave-uniform broadcast loads. Writes
//                      partial (m,l) per 128-j slice; optionally writes scaled
//                      scores S to ws (ws-gated).
//  K2b attn_select_s : stream S -> p -> pbuf -> (verified R2) mix/LN/argmax.
//      attn_select_fb: R2 verified select (recompute path), merge-8 prologue.
//  K2c merge_gather  : unchanged.

#define FMA4(cc, av, bv) \
  cc.x = fmaf(av, bv.x, cc.x); cc.y = fmaf(av, bv.y, cc.y); \
  cc.z = fmaf(av, bv.z, cc.z); cc.w = fmaf(av, bv.w, cc.w);

__global__ __launch_bounds__(256) void qkv_gemm(
    const float* __restrict__ X, const float* __restrict__ Wq,
    const float* __restrict__ Wkv, float* __restrict__ qT,
    float* __restrict__ kT, float* __restrict__ V)
{
  __shared__ __align__(16) float As[16 * 132];
  __shared__ __align__(16) float Bs[16 * 132];
  __shared__ __align__(16) float tb[128 * 32];

  const int t  = threadIdx.x;
  const int bn = blockIdx.x;
  const int bm = blockIdx.y;
  const int m0 = bm * 128, n0 = bn * 128;
  const int ty = t >> 4, tx = t & 15;

  const float* Wbase = (n0 < 1024) ? Wq : Wkv;
  const int nw0 = (n0 < 1024) ? n0 : (n0 - 1024);

  float4 c2[8][2];
#pragma unroll
  for (int a = 0; a < 8; a++) {
    c2[a][0] = make_float4(0.f, 0.f, 0.f, 0.f);
    c2[a][1] = make_float4(0.f, 0.f, 0.f, 0.f);
  }

  const int lr = t >> 1;
  const int lh = t & 1;

  const float4* As4 = (const float4*)As;
  const float4* Bs4 = (const float4*)Bs;

  for (int kb = 0; kb < 64; kb++) {
    const int k0 = kb * 16;
    __syncthreads();
#pragma unroll
    for (int s = 0; s < 2; s++) {
      const int kk = lh * 8 + s * 4;
      float4 av = *(const float4*)&X[(size_t)(m0 + lr) * 1024 + k0 + kk];
      float4 bv = *(const float4*)&Wbase[(size_t)(nw0 + lr) * 1024 + k0 + kk];
      As[(kk + 0) * 132 + lr] = av.x;
      As[(kk + 1) * 132 + lr] = av.y;
      As[(kk + 2) * 132 + lr] = av.z;
      As[(kk + 3) * 132 + lr] = av.w;
      Bs[(kk + 0) * 132 + lr] = bv.x;
      Bs[(kk + 1) * 132 + lr] = bv.y;
      Bs[(kk + 2) * 132 + lr] = bv.z;
      Bs[(kk + 3) * 132 + lr] = bv.w;
    }
    __syncthreads();
#pragma unroll
    for (int kk = 0; kk < 16; kk++) {
      float4 a0 = As4[kk * 33 + ty * 2];
      float4 a1 = As4[kk * 33 + ty * 2 + 1];
      float4 b0 = Bs4[kk * 33 + tx];
      float4 b1 = Bs4[kk * 33 + 16 + tx];
      FMA4(c2[0][0], a0.x, b0); FMA4(c2[0][1], a0.x, b1);
      FMA4(c2[1][0], a0.y, b0); FMA4(c2[1][1], a0.y, b1);
      FMA4(c2[2][0], a0.z, b0); FMA4(c2[2][1], a0.z, b1);
      FMA4(c2[3][0], a0.w, b0); FMA4(c2[3][1], a0.w, b1);
      FMA4(c2[4][0], a1.x, b0); FMA4(c2[4][1], a1.x, b1);
      FMA4(c2[5][0], a1.y, b0); FMA4(c2[5][1], a1.y, b1);
      FMA4(c2[6][0], a1.z, b0); FMA4(c2[6][1], a1.z, b1);
      FMA4(c2[7][0], a1.w, b0); FMA4(c2[7][1], a1.w, b1);
    }
  }

  if (n0 >= 2048) {
    const int nv0 = n0 - 2048;
#pragma unroll
    for (int a = 0; a < 8; a++) {
      *(float4*)&V[(size_t)(m0 + ty * 8 + a) * 1024 + nv0 + tx * 4]      = c2[a][0];
      *(float4*)&V[(size_t)(m0 + ty * 8 + a) * 1024 + nv0 + 64 + tx * 4] = c2[a][1];
    }
    return;
  }

  float* T = (n0 < 1024) ? qT : kT;
  const int nt0 = (n0 < 1024) ? n0 : (n0 - 1024);
  const int bB = m0 >> 10;
  const int i0 = m0 & 1023;
#pragma unroll
  for (int r = 0; r < 4; r++) {
    __syncthreads();
    if ((tx >> 3) == (r & 1)) {
      const int c0 = (tx & 7) * 4;
#pragma unroll
      for (int a = 0; a < 8; a++) {
        const int m = ty * 8 + a;
        float4 val = c2[a][r >> 1];
        tb[m * 32 + ((c0 + 0 + m) & 31)] = val.x;
        tb[m * 32 + ((c0 + 1 + m) & 31)] = val.y;
        tb[m * 32 + ((c0 + 2 + m) & 31)] = val.z;
        tb[m * 32 + ((c0 + 3 + m) & 31)] = val.w;
      }
    }
    __syncthreads();
    const int nl = t >> 3, mq = t & 7;
    float* Trow = T + (size_t)(bB * 1024 + nt0 + (r >> 1) * 64 + (r & 1) * 32 + nl) * 1024 + i0;
#pragma unroll
    for (int l = 0; l < 4; l++) {
      const int mb = (l * 8 + mq) * 4;
      float4 o;
      o.x = tb[(mb + 0) * 32 + ((nl + mb + 0) & 31)];
      o.y = tb[(mb + 1) * 32 + ((nl + mb + 1) & 31)];
      o.z = tb[(mb + 2) * 32 + ((nl + mb + 2) & 31)];
      o.w = tb[(mb + 3) * 32 + ((nl + mb + 3) & 31)];
      *(float4*)(Trow + mb) = o;
    }
  }
}

// ---------------------------------------------------------------------------
// K2a v3: h-loop stats. grid = b(4) x it(32, 32-i tiles) x js(8, 128-j slices).
// block 256 thr = 4 waves; wave w: 8 i (i0w = it*32+w*8) x full 128-j slice
// (2 j per lane). k: LDS double-buffer (16d x 128j chunks). q: broadcast loads.
// Writes Mm/Ml[((b*16+h)*1024+i)*8 + js]; if STORE_S, S[(b*16+h)*1024+i][j].
// d-order ascending 0..63 per (i,j): scores bitwise-identical to R2 path.
// ---------------------------------------------------------------------------
template<int STORE_S>
__global__ __launch_bounds__(256) void attn_stats_v3(
    const float* __restrict__ qT, const float* __restrict__ kT,
    float* __restrict__ Mm, float* __restrict__ Ml, float* __restrict__ S)
{
  __shared__ __align__(16) float kbuf[2][16 * 128];

  const int t  = threadIdx.x;
  const int bx = blockIdx.x;
  const int b  = bx >> 8;
  const int it = (bx >> 3) & 31;
  const int js = bx & 7;
  const int wv = t >> 6;
  const int l  = t & 63;
  const int i0w = __builtin_amdgcn_readfirstlane(it * 32 + wv * 8);
  const int j0 = js * 128;
  const int sd = t >> 4;          // staging d-row 0..15
  const int sc = (t & 15) * 8;    // staging col base

  const float scale = 0.03125f;

  for (int h = 0; h < 16; h++) {
    const size_t krow0 = (size_t)(b * 1024 + h * 64) * 1024 + j0;
    const size_t qrow0 = (size_t)(b * 1024 + h * 64) * 1024 + i0w;

    float acc[8][2];
#pragma unroll
    for (int ii = 0; ii < 8; ii++) { acc[ii][0] = 0.f; acc[ii][1] = 0.f; }

    // stage chunk 0
    {
      const float* src = kT + krow0 + (size_t)sd * 1024 + sc;
      float4 a0 = *(const float4*)src;
      float4 a1 = *(const float4*)(src + 4);
      *(float4*)&kbuf[0][sd * 128 + sc]     = a0;
      *(float4*)&kbuf[0][sd * 128 + sc + 4] = a1;
    }
    __syncthreads();

    for (int dc = 0; dc < 4; dc++) {
      float4 n0, n1;
      if (dc < 3) {
        const float* src = kT + krow0 + (size_t)((dc + 1) * 16 + sd) * 1024 + sc;
        n0 = *(const float4*)src;
        n1 = *(const float4*)(src + 4);
      }
      const float* kb = kbuf[dc & 1];
#pragma unroll
      for (int d = 0; d < 16; d++) {
        const size_t qr = qrow0 + (size_t)(dc * 16 + d) * 1024;
        float4 qa = *(const float4*)&qT[qr];
        float4 qb = *(const float4*)&qT[qr + 4];
        float2 kv = ((const float2*)(kb + d * 128))[l];
        acc[0][0] = fmaf(qa.x, kv.x, acc[0][0]); acc[0][1] = fmaf(qa.x, kv.y, acc[0][1]);
        acc[1][0] = fmaf(qa.y, kv.x, acc[1][0]); acc[1][1] = fmaf(qa.y, kv.y, acc[1][1]);
        acc[2][0] = fmaf(qa.z, kv.x, acc[2][0]); acc[2][1] = fmaf(qa.z, kv.y, acc[2][1]);
        acc[3][0] = fmaf(qa.w, kv.x, acc[3][0]); acc[3][1] = fmaf(qa.w, kv.y, acc[3][1]);
        acc[4][0] = fmaf(qb.x, kv.x, acc[4][0]); acc[4][1] = fmaf(qb.x, kv.y, acc[4][1]);
        acc[5][0] = fmaf(qb.y, kv.x, acc[5][0]); acc[5][1] = fmaf(qb.y, kv.y, acc[5][1]);
        acc[6][0] = fmaf(qb.z, kv.x, acc[6][0]); acc[6][1] = fmaf(qb.z, kv.y, acc[6][1]);
        acc[7][0] = fmaf(qb.w, kv.x, acc[7][0]); acc[7][1] = fmaf(qb.w, kv.y, acc[7][1]);
      }
      if (dc < 3) {
        *(float4*)&kbuf[(dc + 1) & 1][sd * 128 + sc]     = n0;
        *(float4*)&kbuf[(dc + 1) & 1][sd * 128 + sc + 4] = n1;
      }
      __syncthreads();
    }

    // per-h epilogue: wave-reduce (m,l) over 128 j; optional S store
#pragma unroll
    for (int ii = 0; ii < 8; ii++) {
      const float s0 = acc[ii][0] * scale;
      const float s1 = acc[ii][1] * scale;
      if (STORE_S) {
        float2 sv; sv.x = s0; sv.y = s1;
        *(float2*)&S[(size_t)((b * 16 + h) * 1024 + i0w + ii) * 1024 + j0 + 2 * l] = sv;
      }
      float mx = fmaxf(s0, s1);
      mx = fmaxf(mx, __shfl_xor(mx, 1));
      mx = fmaxf(mx, __shfl_xor(mx, 2));
      mx = fmaxf(mx, __shfl_xor(mx, 4));
      mx = fmaxf(mx, __shfl_xor(mx, 8));
      mx = fmaxf(mx, __shfl_xor(mx, 16));
      mx = fmaxf(mx, __shfl_xor(mx, 32));
      float ss = __expf(s0 - mx) + __expf(s1 - mx);
      ss += __shfl_xor(ss, 1);
      ss += __shfl_xor(ss, 2);
      ss += __shfl_xor(ss, 4);
      ss += __shfl_xor(ss, 8);
      ss += __shfl_xor(ss, 16);
      ss += __shfl_xor(ss, 32);
      if (l == ii) {
        const int idx = (((b * 16 + h) * 1024 + i0w + ii) << 3) + js;
        Mm[idx] = mx;
        Ml[idx] = ss;
      }
    }
  }
}

// ---------------------------------------------------------------------------
// K2b (fast path): stream S -> p -> pbuf -> mix/LN/argmax (verified R2 code).
// grid = b(4) x it(64, 16-i) x js(4, 256-j). 8 j-chunks of 32; 2 barriers/chunk.
// ---------------------------------------------------------------------------
__global__ __launch_bounds__(256) void attn_select_s(
    const float* __restrict__ S, const float* __restrict__ Mm,
    const float* __restrict__ Ml, const float* __restrict__ Wt,
    const float* __restrict__ ln_g, const float* __restrict__ ln_b,
    float* __restrict__ Aval, int* __restrict__ Aidx)
{
  __shared__ __align__(16) float pbuf[8800];   // j*275 + i*17 + h

  const int t  = threadIdx.x;
  const int bx = blockIdx.x;
  const int b  = bx >> 8;
  const int it = (bx >> 2) & 63;
  const int js = bx & 3;
  const int i0 = it << 4;
  const int j0 = js << 8;

  const int ip  = t >> 4;          // p-phase & mix-phase i (0..15)
  const int jj2 = (t & 15) * 2;    // p-phase j pair within 32-chunk
  const int i2 = t >> 4;           // mix-phase (R2 verified mapping)
  const int g  = (t >> 2) & 3;
  const int hq = t & 3;

  // merge-8 stats into registers (thread's i = ip fixed)
  float m_r[16], rl_r[16];
#pragma unroll
  for (int h = 0; h < 16; h++) {
    const int base = (((b * 16 + h) * 1024 + i0 + ip) << 3);
    const float4 ma = *(const float4*)&Mm[base];
    const float4 mb = *(const float4*)&Mm[base + 4];
    const float4 la = *(const float4*)&Ml[base];
    const float4 lb = *(const float4*)&Ml[base + 4];
    float M = fmaxf(fmaxf(fmaxf(ma.x, ma.y), fmaxf(ma.z, ma.w)),
                    fmaxf(fmaxf(mb.x, mb.y), fmaxf(mb.z, mb.w)));
    float L = la.x * __expf(ma.x - M) + la.y * __expf(ma.y - M) +
              la.z * __expf(ma.z - M) + la.w * __expf(ma.w - M) +
              lb.x * __expf(mb.x - M) + lb.y * __expf(mb.y - M) +
              lb.z * __expf(mb.z - M) + lb.w * __expf(mb.w - M);
    m_r[h]  = M;
    rl_r[h] = 1.0f / L;
  }

  float wtr[4][16], gr[4], br[4];
#pragma unroll
  for (int a = 0; a < 4; a++) {
#pragma unroll
    for (int h2 = 0; h2 < 16; h2++) wtr[a][h2] = Wt[(hq * 4 + a) * 16 + h2];
    gr[a] = ln_g[hq * 4 + a];
    br[a] = ln_b[hq * 4 + a];
  }
  float bv[4]; int bix[4];
#pragma unroll
  for (int a = 0; a < 4; a++) { bv[a] = -1e30f; bix[a] = 0; }

  for (int jc = 0; jc < 8; jc++) {
#pragma unroll
    for (int h = 0; h < 16; h++) {
      const float2 sv = *(const float2*)&S[
          (size_t)((b * 16 + h) * 1024 + i0 + ip) * 1024 + j0 + jc * 32 + jj2];
      const float p0 = __expf(sv.x - m_r[h]) * rl_r[h];
      const float p1 = __expf(sv.y - m_r[h]) * rl_r[h];
      pbuf[(jj2 + 0) * 275 + ip * 17 + h] = p0;
      pbuf[(jj2 + 1) * 275 + ip * 17 + h] = p1;
    }
    __syncthreads();
    // ---- verified R2 mix/LN/argmax ----
#pragma unroll
    for (int jj = 0; jj < 8; jj++) {
      const int j = g * 8 + jj;
      float pv[16];
#pragma unroll
      for (int h2 = 0; h2 < 16; h2++) pv[h2] = pbuf[j * 275 + i2 * 17 + h2];
      float mix[4];
#pragma unroll
      for (int a = 0; a < 4; a++) {
        float s0 = 0.f;
#pragma unroll
        for (int h2 = 0; h2 < 16; h2++) s0 = fmaf(pv[h2], wtr[a][h2], s0);
        mix[a] = s0;
      }
      float s1 = mix[0] + mix[1] + mix[2] + mix[3];
      s1 += __shfl_xor(s1, 1);
      s1 += __shfl_xor(s1, 2);
      const float mu = s1 * 0.0625f;
      float s2 = 0.f;
#pragma unroll
      for (int a = 0; a < 4; a++) { const float dd = mix[a] - mu; s2 = fmaf(dd, dd, s2); }
      s2 += __shfl_xor(s2, 1);
      s2 += __shfl_xor(s2, 2);
      const float rstd = rsqrtf(s2 * 0.0625f + 1e-5f);
      const int jg = j0 + jc * 32 + j;
#pragma unroll
      for (int a = 0; a < 4; a++) {
        const float nv = (mix[a] - mu) * rstd * gr[a] + br[a];
        if (nv > bv[a]) { bv[a] = nv; bix[a] = jg; }
      }
    }
    __syncthreads();
  }

#pragma unroll
  for (int a = 0; a < 4; a++) {
    float v = bv[a]; int ix = bix[a];
    {
      const float ov = __shfl_xor(v, 4);
      const int oi = __shfl_xor(ix, 4);
      if (ov > v || (ov == v && oi < ix)) { v = ov; ix = oi; }
    }
    {
      const float ov = __shfl_xor(v, 8);
      const int oi = __shfl_xor(ix, 8);
      if (ov > v || (ov == v && oi < ix)) { v = ov; ix = oi; }
    }
    bv[a] = v; bix[a] = ix;
  }

  if (g == 0) {
#pragma unroll
    for (int a = 0; a < 4; a++) {
      const int idx = bx * 256 + (hq * 4 + a) * 16 + i2;
      Aval[idx] = bv[a];
      Aidx[idx] = bix[a];
    }
  }
}

// ---------------------------------------------------------------------------
// K2b (fallback, ws too small): R2 verified recompute-select; only the stats
// prologue changed to merge 8 slices from the new Mm/Ml layout.
// ---------------------------------------------------------------------------
__global__ __launch_bounds__(256) void attn_select_fb(
    const float* __restrict__ qT, const float* __restrict__ kT,
    const float* __restrict__ Wt, const float* __restrict__ ln_g,
    const float* __restrict__ ln_b, const float* __restrict__ Mm,
    const float* __restrict__ Ml, float* __restrict__ Aval,
    int* __restrict__ Aidx)
{
  __shared__ __align__(16) float smem[12992];
  float* qch  = smem;
  float* kch  = smem + 4224;
  float* pbuf = smem;
  float* mred = smem + 12480;
  float* rred = smem + 12736;

  const int t  = threadIdx.x;
  const int bx = blockIdx.x;
  const int b  = bx >> 8;
  const int it = (bx >> 2) & 63;
  const int js = bx & 3;
  const int i0 = it << 4;

  const int h  = t >> 4;
  const int mi = (t >> 2) & 3;
  const int mj = t & 3;
  const int sd = t & 15;
  const int i2 = t >> 4;
  const int g  = (t >> 2) & 3;
  const int hq = t & 3;

  const float scale = 0.03125f;

  {
    const int base = (((b * 16 + (t >> 4)) * 1024 + i0 + (t & 15)) << 3);
    const float4 ma = *(const float4*)&Mm[base];
    const float4 mb = *(const float4*)&Mm[base + 4];
    const float4 la = *(const float4*)&Ml[base];
    const float4 lb = *(const float4*)&Ml[base + 4];
    float M = fmaxf(fmaxf(fmaxf(ma.x, ma.y), fmaxf(ma.z, ma.w)),
                    fmaxf(fmaxf(mb.x, mb.y), fmaxf(mb.z, mb.w)));
    float L = la.x * __expf(ma.x - M) + la.y * __expf(ma.y - M) +
              la.z * __expf(ma.z - M) + la.w * __expf(ma.w - M) +
              lb.x * __expf(mb.x - M) + lb.y * __expf(mb.y - M) +
              lb.z * __expf(mb.z - M) + lb.w * __expf(mb.w - M);
    mred[t] = M;
    rred[t] = 1.0f / L;
  }
  __syncthreads();
  float m_fin[4], rl_fin[4];
#pragma unroll
  for (int ii = 0; ii < 4; ii++) {
    m_fin[ii]  = mred[h * 16 + mi * 4 + ii];
    rl_fin[ii] = rred[h * 16 + mi * 4 + ii];
  }

  auto stage = [&](int cc, int jt) {
    const size_t row = (size_t)(b * 1024 + h * 64 + cc * 16 + sd) * 1024;
    const int s = (sd >> 1) & 3;
    const float* qsrc = qT + row + i0;
#pragma unroll
    for (int blk = 0; blk < 4; blk++)
      *(float4*)&qch[h * 264 + sd * 16 + (((blk ^ s) & 3) << 2)] =
          *(const float4*)(qsrc + blk * 4);
    const float* ksrc = kT + row + jt * 32;
#pragma unroll
    for (int blk = 0; blk < 8; blk++)
      *(float4*)&kch[h * 516 + sd * 32 + (((blk ^ s) & 7) << 2)] =
          *(const float4*)(ksrc + blk * 4);
  };

  auto dotstep = [&](float (&acc)[4][8]) {
#pragma unroll
    for (int d = 0; d < 16; d++) {
      const int s = (d >> 1) & 3;
      float4 qv = *(const float4*)&qch[h * 264 + d * 16 + (((mi ^ s) & 3) << 2)];
      float4 ka = *(const float4*)&kch[h * 516 + d * 32 + ((((2 * mj) ^ s) & 7) << 2)];
      float4 kb = *(const float4*)&kch[h * 516 + d * 32 + ((((2 * mj + 1) ^ s) & 7) << 2)];
      const float qa[4] = {qv.x, qv.y, qv.z, qv.w};
#pragma unroll
      for (int ii = 0; ii < 4; ii++) {
        const float qi = qa[ii];
        acc[ii][0] = fmaf(qi, ka.x, acc[ii][0]);
        acc[ii][1] = fmaf(qi, ka.y, acc[ii][1]);
        acc[ii][2] = fmaf(qi, ka.z, acc[ii][2]);
        acc[ii][3] = fmaf(qi, ka.w, acc[ii][3]);
        acc[ii][4] = fmaf(qi, kb.x, acc[ii][4]);
        acc[ii][5] = fmaf(qi, kb.y, acc[ii][5]);
        acc[ii][6] = fmaf(qi, kb.z, acc[ii][6]);
        acc[ii][7] = fmaf(qi, kb.w, acc[ii][7]);
      }
    }
  };

  float wtr[4][16], gr[4], br[4];
#pragma unroll
  for (int a = 0; a < 4; a++) {
#pragma unroll
    for (int h2 = 0; h2 < 16; h2++) wtr[a][h2] = Wt[(hq * 4 + a) * 16 + h2];
    gr[a] = ln_g[hq * 4 + a];
    br[a] = ln_b[hq * 4 + a];
  }
  float bv[4]; int bix[4];
#pragma unroll
  for (int a = 0; a < 4; a++) { bv[a] = -1e30f; bix[a] = 0; }

  for (int jtl = 0; jtl < 8; jtl++) {
    const int jt = js * 8 + jtl;
    float acc[4][8];
#pragma unroll
    for (int ii = 0; ii < 4; ii++)
#pragma unroll
      for (int jj = 0; jj < 8; jj++) acc[ii][jj] = 0.f;
    for (int cc = 0; cc < 4; cc++) {
      __syncthreads();
      stage(cc, jt);
      __syncthreads();
      dotstep(acc);
    }
    __syncthreads();
#pragma unroll
    for (int ii = 0; ii < 4; ii++) {
#pragma unroll
      for (int jj = 0; jj < 8; jj++) {
        const float p = __expf(acc[ii][jj] * scale - m_fin[ii]) * rl_fin[ii];
        pbuf[(mj * 8 + jj) * 275 + (mi * 4 + ii) * 17 + h] = p;
      }
    }
    __syncthreads();
#pragma unroll
    for (int jj = 0; jj < 8; jj++) {
      const int j = g * 8 + jj;
      float pv[16];
#pragma unroll
      for (int h2 = 0; h2 < 16; h2++) pv[h2] = pbuf[j * 275 + i2 * 17 + h2];
      float mix[4];
#pragma unroll
      for (int a = 0; a < 4; a++) {
        float s0 = 0.f;
#pragma unroll
        for (int h2 = 0; h2 < 16; h2++) s0 = fmaf(pv[h2], wtr[a][h2], s0);
        mix[a] = s0;
      }
      float s1 = mix[0] + mix[1] + mix[2] + mix[3];
      s1 += __shfl_xor(s1, 1);
      s1 += __shfl_xor(s1, 2);
      const float mu = s1 * 0.0625f;
      float s2 = 0.f;
#pragma unroll
      for (int a = 0; a < 4; a++) { const float dd = mix[a] - mu; s2 = fmaf(dd, dd, s2); }
      s2 += __shfl_xor(s2, 1);
      s2 += __shfl_xor(s2, 2);
      const float rstd = rsqrtf(s2 * 0.0625f + 1e-5f);
      const int jg = jt * 32 + j;
#pragma unroll
      for (int a = 0; a < 4; a++) {
        const float nv = (mix[a] - mu) * rstd * gr[a] + br[a];
        if (nv > bv[a]) { bv[a] = nv; bix[a] = jg; }
      }
    }
  }

#pragma unroll
  for (int a = 0; a < 4; a++) {
    float v = bv[a]; int ix = bix[a];
    {
      const float ov = __shfl_xor(v, 4);
      const int oi = __shfl_xor(ix, 4);
      if (ov > v || (ov == v && oi < ix)) { v = ov; ix = oi; }
    }
    {
      const float ov = __shfl_xor(v, 8);
      const int oi = __shfl_xor(ix, 8);
      if (ov > v || (ov == v && oi < ix)) { v = ov; ix = oi; }
    }
    bv[a] = v; bix[a] = ix;
  }

  if (g == 0) {
#pragma unroll
    for (int a = 0; a < 4; a++) {
      const int idx = bx * 256 + (hq * 4 + a) * 16 + i2;
      Aval[idx] = bv[a];
      Aidx[idx] = bix[a];
    }
  }
}

// ---------------------------------------------------------------------------
// K2c: merge the 4 j-slices' argmax, gather V rows to out.
// ---------------------------------------------------------------------------
__global__ __launch_bounds__(256) void merge_gather(
    const float* __restrict__ Aval, const int* __restrict__ Aidx,
    const float* __restrict__ V, float* __restrict__ out)
{
  const int t  = threadIdx.x;
  const int bx = blockIdx.x;
  const int b  = bx >> 6;
  const int it = bx & 63;
  const int i2 = t >> 4;
  const int h  = t & 15;

  const int base = ((b * 64 + it) << 2) * 256 + h * 16 + i2;
  float bvv = Aval[base];
  int   bii = Aidx[base];
#pragma unroll
  for (int s = 1; s < 4; s++) {
    const float v = Aval[base + s * 256];
    const int   x = Aidx[base + s * 256];
    if (v > bvv) { bvv = v; bii = x; }
  }

  const float* vs = V + (size_t)(b * 1024 + bii) * 1024 + h * 64;
  float* dst = out + (size_t)(b * 1024 + it * 16 + i2) * 1024 + h * 64;
#pragma unroll
  for (int w = 0; w < 16; w++)
    *(float4*)(dst + w * 4) = *(const float4*)(vs + w * 4);
}

extern "C" void kernel_launch(void* const* d_in, const int* in_sizes, int n_in,
                              void* d_out, int out_size, void* d_ws, size_t ws_size,
                              hipStream_t stream) {
  const float* x   = (const float*)d_in[0];
  const float* Wq  = (const float*)d_in[1];
  const float* Wkv = (const float*)d_in[2];
  const float* Wt  = (const float*)d_in[3];
  const float* lng = (const float*)d_in[4];
  const float* lnb = (const float*)d_in[5];
  float* out = (float*)d_out;
  float* ws  = (float*)d_ws;
  float* qT   = ws;                                    // 4M f
  float* kT   = ws + (size_t)4 * 1024 * 1024;          // 4M f
  float* V    = ws + (size_t)8 * 1024 * 1024;          // 4M f
  float* Mm   = ws + (size_t)12 * 1024 * 1024;         // 512K f
  float* Ml   = Mm + 524288;                           // 512K f
  float* Aval = ws + (size_t)13 * 1024 * 1024;         // 256K f
  int*   Aidx = (int*)(Aval + 262144);                 // 256K
  float* S    = ws + (size_t)14 * 1024 * 1024;         // 64M f (gated)

  const size_t need_s = ((size_t)14 * 1024 * 1024 + (size_t)64 * 1024 * 1024) * 4;
  const bool useS = ws_size >= need_s;

  hipLaunchKernelGGL(qkv_gemm, dim3(24, 32), dim3(256), 0, stream,
                     x, Wq, Wkv, qT, kT, V);
  if (useS) {
    hipLaunchKernelGGL((attn_stats_v3<1>), dim3(1024), dim3(256), 0, stream,
                       qT, kT, Mm, Ml, S);
    hipLaunchKernelGGL(attn_select_s, dim3(1024), dim3(256), 0, stream,
                       S, Mm, Ml, Wt, lng, lnb, Aval, Aidx);
  } else {
    hipLaunchKernelGGL((attn_stats_v3<0>), dim3(1024), dim3(256), 0, stream,
                       qT, kT, Mm, Ml, S);
    hipLaunchKernelGGL(attn_select_fb, dim3(1024), dim3(256), 0, stream,
                       qT, kT, Wt, lng, lnb, Mm, Ml, Aval, Aidx);
  }
  hipLaunchKernelGGL(merge_gather, dim3(256), dim3(256), 0, stream,
                     Aval, Aidx, V, out);
}